// Round 17
// baseline (602.422 us; speedup 1.0000x reference)
//
#include <hip/hip_runtime.h>
#include <math.h>

// Problem constants (from reference)
constexpr int B    = 512;
constexpr int NPG  = 200;    // nodes per graph, stage 0
constexpr int EPER = 2000;   // edges per graph
constexpr int EMB  = 9;
constexpr int HID  = 128;
constexpr int K1   = 160;    // ceil(0.8*200)
constexpr int K2   = 128;    // ceil(0.8*160)
constexpr int K3   = 103;    // ceil(0.8*128)
constexpr int E    = B * EPER;  // 1024000

// Exclusive prefix scan over 256 ints by wave 0 (4 vals/lane + shfl_up).
__device__ __forceinline__ void scan_off(const int* deg, int* off2,
                                         int lane, int wv) {
    if (wv == 0) {
        int i0 = lane * 4;
        int v0 = deg[i0], v1 = deg[i0 + 1], v2 = deg[i0 + 2], v3 = deg[i0 + 3];
        int s1 = v0 + v1, s2 = s1 + v2, s3 = s2 + v3;
        int run = s3;
        #pragma unroll
        for (int o = 1; o < 64; o <<= 1) {
            int t = __shfl_up(run, o, 64);
            if (lane >= o) run += t;
        }
        int excl = run - s3;
        off2[i0]     = excl;
        off2[i0 + 1] = excl + v0;
        off2[i0 + 2] = excl + s1;
        off2[i0 + 3] = excl + s2;
        if (lane == 63) off2[256] = run;
    }
}

// ---------------------------------------------------------------------------
// ONE KERNEL for all three GNN stages, one graph per block.
// r17: 1024 threads (16 waves) with 5x4 / 4x4 register tiles.
// Rationale: r13-r16 all spilled ~30MB scratch with the 8x4 twin-accumulator
// tile (live set ~140 floats) no matter the launch bounds — the allocator
// pins at 84 VGPRs and spills. Smaller per-thread tiles cut the live set to
// ~90 floats AND double waves/SIMD (2.5 -> 4) for latency hiding.
// Tripwire: WRITE_SIZE should drop 34.5MB -> ~1.6MB logical.
// GEMM K-loop layout is the r4/r7/r13-verified k-major transposed form
// (do NOT XOR-swizzle: r5/r6 spill pathology).
__global__ __launch_bounds__(1024, 1) void k_fused(
        const int* __restrict__ node_ids,
        const float* __restrict__ emb,
        const int* __restrict__ es, const int* __restrict__ ed,
        const float* __restrict__ w1n, const float* __restrict__ w1r,
        const float* __restrict__ b1, const float* __restrict__ p1,
        const float* __restrict__ w2n, const float* __restrict__ w2r,
        const float* __restrict__ b2, const float* __restrict__ p2,
        const float* __restrict__ w3n, const float* __restrict__ w3r,
        const float* __restrict__ b3, const float* __restrict__ p3,
        float* __restrict__ g1, float* __restrict__ g2,
        float* __restrict__ g3) {
    const int g = blockIdx.x, tid = threadIdx.x;
    const int lane = tid & 63, wv = tid >> 6;   // 16 waves

    __shared__ float xY[K1 * 132];              // 84.5 KB
    __shared__ float S[2 * 32 * 132];           // 33.8 KB scratch union (8448)
    __shared__ int   csr[EPER];                 // 8 KB
    __shared__ int   deg[256], off2[257], cur[256];
    __shared__ int   idsL[NPG];                 // reused as posC in phase C
    __shared__ float sc[NPG];
    __shared__ int   pos1[NPG], pos2[K1];

    const int eb = g * EPER, nb0 = g * NPG;

    // ======================= Phase A: stage 1 =======================
    {
        float* x0L  = S;          // 1800
        float* mnL  = S + 1800;   // 1800
        float* redA = S + 3600;   // 4096 = 16*128*2
        if (tid < NPG) idsL[tid] = node_ids[g * NPG + tid];
        if (tid < 256) deg[tid] = 0;
        __syncthreads();
        for (int i = tid; i < NPG * EMB; i += 1024) {
            int n = i / EMB, j = i - n * EMB;
            x0L[i] = emb[(size_t)idsL[n] * EMB + j];
        }
        for (int e = tid; e < EPER; e += 1024)
            atomicAdd(&deg[ed[eb + e] - nb0], 1);
        __syncthreads();
        scan_off(deg, off2, lane, wv);
        __syncthreads();
        if (tid < 256) cur[tid] = off2[tid];
        __syncthreads();
        for (int e = tid; e < EPER; e += 1024) {
            int slot = atomicAdd(&cur[ed[eb + e] - nb0], 1);
            csr[slot] = es[eb + e] - nb0;
        }
        __syncthreads();
        if (tid < NPG) {
            int bg = off2[tid], en = off2[tid + 1];
            float a[EMB];
            #pragma unroll
            for (int j = 0; j < EMB; j++) a[j] = 0.f;
            for (int t = bg; t < en; t++) {
                int s = csr[t];
                #pragma unroll
                for (int j = 0; j < EMB; j++) a[j] += x0L[s * EMB + j];
            }
            float inv = 1.f / (float)((en - bg) > 1 ? (en - bg) : 1);
            #pragma unroll
            for (int j = 0; j < EMB; j++) mnL[tid * EMB + j] = a[j] * inv;
        }
        float pl0 = p1[lane], pl1 = p1[64 + lane];
        float pp = pl0 * pl0 + pl1 * pl1;
        #pragma unroll
        for (int o = 32; o >= 1; o >>= 1) pp += __shfl_xor(pp, o, 64);
        float nrm = sqrtf(pp);
        float wn0[EMB], wn1[EMB], wr0[EMB], wr1[EMB];
        #pragma unroll
        for (int j = 0; j < EMB; j++) {
            wn0[j] = w1n[lane * EMB + j];
            wn1[j] = w1n[(lane + 64) * EMB + j];
            wr0[j] = w1r[lane * EMB + j];
            wr1[j] = w1r[(lane + 64) * EMB + j];
        }
        float bb0 = b1[lane], bb1 = b1[64 + lane];
        __syncthreads();
        for (int i = wv; i < NPG; i += 16) {
            float c0 = bb0, c1 = bb1;
            #pragma unroll
            for (int j = 0; j < EMB; j++) {
                float m = mnL[i * EMB + j];
                float x = x0L[i * EMB + j];
                c0 += m * wn0[j] + x * wr0[j];
                c1 += m * wn1[j] + x * wr1[j];
            }
            c0 = fmaxf(c0, 0.f);
            c1 = fmaxf(c1, 0.f);
            float d = c0 * pl0 + c1 * pl1;
            #pragma unroll
            for (int o = 32; o >= 1; o >>= 1) d += __shfl_xor(d, o, 64);
            if (lane == 0) sc[i] = tanhf(d / nrm);
        }
        __syncthreads();
        if (tid < NPG) {
            float scv = sc[tid];
            int rank = 0;
            for (int j = 0; j < NPG; j++) {
                float o = sc[j];
                rank += (o > scv) || (o == scv && j < tid);
            }
            pos1[tid] = (rank < K1) ? rank : -1;
        }
        __syncthreads();
        float pm0 = -INFINITY, pm1 = -INFINITY, ps0 = 0.f, ps1 = 0.f;
        for (int i = wv; i < NPG; i += 16) {
            int r = pos1[i];
            if (r < 0) continue;
            float c0 = bb0, c1 = bb1;
            #pragma unroll
            for (int j = 0; j < EMB; j++) {
                float m = mnL[i * EMB + j];
                float x = x0L[i * EMB + j];
                c0 += m * wn0[j] + x * wr0[j];
                c1 += m * wn1[j] + x * wr1[j];
            }
            float s = sc[i];
            float v0 = fmaxf(c0, 0.f) * s;
            float v1 = fmaxf(c1, 0.f) * s;
            xY[r * 132 + lane] = v0;
            xY[r * 132 + 64 + lane] = v1;
            pm0 = fmaxf(pm0, v0); ps0 += v0;
            pm1 = fmaxf(pm1, v1); ps1 += v1;
        }
        redA[wv * 128 + lane] = pm0;
        redA[wv * 128 + 64 + lane] = pm1;
        redA[2048 + wv * 128 + lane] = ps0;
        redA[2048 + wv * 128 + 64 + lane] = ps1;
        __syncthreads();
        if (tid < 128) {
            float mx = redA[tid], sm = redA[2048 + tid];
            #pragma unroll
            for (int w = 1; w < 16; w++) {
                mx = fmaxf(mx, redA[w * 128 + tid]);
                sm += redA[2048 + w * 128 + tid];
            }
            g1[g * 256 + tid] = mx;
            g1[g * 256 + 128 + tid] = sm / (float)K1;
        }
        __syncthreads();
    }

    // ======================= Phase B: stage 2 =======================
    {
        if (tid < 256) deg[tid] = 0;
        __syncthreads();
        for (int e = tid; e < EPER; e += 1024) {
            int a = pos1[es[eb + e] - nb0];
            int b = pos1[ed[eb + e] - nb0];
            if (a >= 0 && b >= 0) atomicAdd(&deg[b], 1);
        }
        __syncthreads();
        scan_off(deg, off2, lane, wv);
        __syncthreads();
        if (tid < 256) cur[tid] = off2[tid];
        __syncthreads();
        for (int e = tid; e < EPER; e += 1024) {
            int a = pos1[es[eb + e] - nb0];
            int b = pos1[ed[eb + e] - nb0];
            if (a >= 0 && b >= 0) {
                int slot = atomicAdd(&cur[b], 1);
                csr[slot] = a;
            }
        }
        __syncthreads();

        const int tc = tid & 31, tr = tid >> 5;   // tr 0..31, 5 rows each
        float accY[5][4], accZ[5][4];
        #pragma unroll
        for (int r = 0; r < 5; r++)
            #pragma unroll
            for (int c = 0; c < 4; c++) { accY[r][c] = 0.f; accZ[r][c] = 0.f; }

        const int sr = tid >> 3, sc4 = (tid & 7) * 4;
        const bool stager = (sr < 64);
        const float* wsrc0 = (sr < 32) ? w2n : w2r;
        const int wrow = (sr < 32) ? sr : sr - 32;
        float* Bmine = S + ((sr < 32) ? 0 : 32 * 132);
        float4 bvv[4];
        if (stager) {
            #pragma unroll
            for (int i = 0; i < 4; i++)
                bvv[i] = *(const float4*)(wsrc0 + (size_t)(wrow + i * 32) * HID + sc4);
        }
        for (int ch = 0; ch < 4; ch++) {
            if (stager) {
                #pragma unroll
                for (int i = 0; i < 4; i++) {
                    int r = wrow + i * 32;
                    Bmine[(sc4 + 0) * 132 + r] = bvv[i].x;
                    Bmine[(sc4 + 1) * 132 + r] = bvv[i].y;
                    Bmine[(sc4 + 2) * 132 + r] = bvv[i].z;
                    Bmine[(sc4 + 3) * 132 + r] = bvv[i].w;
                }
            }
            __syncthreads();
            if (ch + 1 < 4 && stager) {
                #pragma unroll
                for (int i = 0; i < 4; i++)
                    bvv[i] = *(const float4*)(wsrc0 + (size_t)(wrow + i * 32) * HID
                                              + (ch + 1) * 32 + sc4);
            }
            for (int kq = 0; kq < 8; kq++) {
                float4 af[5];
                #pragma unroll
                for (int rr = 0; rr < 5; rr++)
                    af[rr] = *(const float4*)&xY[(tr * 5 + rr) * 132 + ch * 32 + kq * 4];
                #pragma unroll
                for (int kk = 0; kk < 4; kk++) {
                    int k = kq * 4 + kk;
                    float4 bn = *(const float4*)&S[k * 132 + tc * 4];
                    float4 br = *(const float4*)&S[32 * 132 + k * 132 + tc * 4];
                    #pragma unroll
                    for (int rr = 0; rr < 5; rr++) {
                        float a = (kk == 0) ? af[rr].x : (kk == 1) ? af[rr].y
                                 : (kk == 2) ? af[rr].z : af[rr].w;
                        accY[rr][0] += a * bn.x; accY[rr][1] += a * bn.y;
                        accY[rr][2] += a * bn.z; accY[rr][3] += a * bn.w;
                        accZ[rr][0] += a * br.x; accZ[rr][1] += a * br.y;
                        accZ[rr][2] += a * br.z; accZ[rr][3] += a * br.w;
                    }
                }
            }
            __syncthreads();
        }
        #pragma unroll
        for (int rr = 0; rr < 5; rr++) {
            float4 yv = {accY[rr][0], accY[rr][1], accY[rr][2], accY[rr][3]};
            *(float4*)&xY[(tr * 5 + rr) * 132 + tc * 4] = yv;
        }
        __syncthreads();

        float bias[4], pv[4];
        #pragma unroll
        for (int c = 0; c < 4; c++) {
            bias[c] = b2[tc * 4 + c];
            pv[c]   = p2[tc * 4 + c];
        }
        float a0 = p2[lane], a1 = p2[64 + lane];
        float pp = a0 * a0 + a1 * a1;
        #pragma unroll
        for (int o = 32; o >= 1; o >>= 1) pp += __shfl_xor(pp, o, 64);
        float nrm = sqrtf(pp);
        float outv[5][4];
        #pragma unroll
        for (int rr = 0; rr < 5; rr++) {
            int m = tr * 5 + rr;
            int bg = off2[m], en = off2[m + 1];
            float s0 = 0.f, s1 = 0.f, s2 = 0.f, s3 = 0.f;
            for (int t = bg; t < en; t++) {
                float4 yv = *(const float4*)&xY[csr[t] * 132 + tc * 4];
                s0 += yv.x; s1 += yv.y; s2 += yv.z; s3 += yv.w;
            }
            float inv = 1.f / (float)((en - bg) > 1 ? (en - bg) : 1);
            outv[rr][0] = fmaxf(s0 * inv + accZ[rr][0] + bias[0], 0.f);
            outv[rr][1] = fmaxf(s1 * inv + accZ[rr][1] + bias[1], 0.f);
            outv[rr][2] = fmaxf(s2 * inv + accZ[rr][2] + bias[2], 0.f);
            outv[rr][3] = fmaxf(s3 * inv + accZ[rr][3] + bias[3], 0.f);
        }
        float* scpart = S;   // 160*32 = 5120 <= 8448
        __syncthreads();
        #pragma unroll
        for (int rr = 0; rr < 5; rr++) {
            float sp = outv[rr][0] * pv[0] + outv[rr][1] * pv[1]
                     + outv[rr][2] * pv[2] + outv[rr][3] * pv[3];
            scpart[(tr * 5 + rr) * 32 + tc] = sp;
        }
        __syncthreads();
        if (tid < K1) {
            float sum = 0.f;
            #pragma unroll
            for (int t = 0; t < 32; t++) sum += scpart[tid * 32 + t];
            sc[tid] = tanhf(sum / nrm);
        }
        __syncthreads();
        if (tid < K1) {
            float scv = sc[tid];
            int rank = 0;
            for (int j = 0; j < K1; j++) {
                float o = sc[j];
                rank += (o > scv) || (o == scv && j < tid);
            }
            pos2[tid] = (rank < K2) ? rank : -1;
        }
        __syncthreads();
        float cm[4], cs[4];
        #pragma unroll
        for (int c = 0; c < 4; c++) { cm[c] = -INFINITY; cs[c] = 0.f; }
        #pragma unroll
        for (int rr = 0; rr < 5; rr++) {
            int m = tr * 5 + rr;
            int r = pos2[m];
            if (r < 0) continue;
            float sv = sc[m];
            float v0 = outv[rr][0] * sv, v1 = outv[rr][1] * sv;
            float v2 = outv[rr][2] * sv, v3 = outv[rr][3] * sv;
            cm[0] = fmaxf(cm[0], v0); cs[0] += v0;
            cm[1] = fmaxf(cm[1], v1); cs[1] += v1;
            cm[2] = fmaxf(cm[2], v2); cs[2] += v2;
            cm[3] = fmaxf(cm[3], v3); cs[3] += v3;
            float4 o0 = {v0, v1, v2, v3};
            *(float4*)&xY[r * 132 + tc * 4] = o0;   // x2p stays in LDS
        }
        __syncthreads();   // scpart dead before redM/redS reuse
        float* redM = S;                 // 32*128 = 4096
        float* redS = S + 32 * 128;      // 4096 (total 8192 <= 8448)
        #pragma unroll
        for (int c = 0; c < 4; c++) {
            redM[tr * 128 + tc * 4 + c] = cm[c];
            redS[tr * 128 + tc * 4 + c] = cs[c];
        }
        __syncthreads();
        if (tid < 128) {
            float mx = redM[tid], sm = redS[tid];
            #pragma unroll 4
            for (int t = 1; t < 32; t++) {
                mx = fmaxf(mx, redM[t * 128 + tid]);
                sm += redS[t * 128 + tid];
            }
            g2[g * 256 + tid] = mx;
            g2[g * 256 + 128 + tid] = sm / (float)K2;
        }
        __syncthreads();
    }

    // ======================= Phase C: stage 3 =======================
    {
        if (tid < 256) deg[tid] = 0;
        __syncthreads();
        for (int e = tid; e < EPER; e += 1024) {
            int a = pos1[es[eb + e] - nb0];
            int b = pos1[ed[eb + e] - nb0];
            a = (a >= 0) ? pos2[a] : -1;
            b = (b >= 0) ? pos2[b] : -1;
            if (a >= 0 && b >= 0) atomicAdd(&deg[b], 1);
        }
        __syncthreads();
        scan_off(deg, off2, lane, wv);
        __syncthreads();
        if (tid < 256) cur[tid] = off2[tid];
        __syncthreads();
        for (int e = tid; e < EPER; e += 1024) {
            int a = pos1[es[eb + e] - nb0];
            int b = pos1[ed[eb + e] - nb0];
            a = (a >= 0) ? pos2[a] : -1;
            b = (b >= 0) ? pos2[b] : -1;
            if (a >= 0 && b >= 0) {
                int slot = atomicAdd(&cur[b], 1);
                csr[slot] = a;
            }
        }
        __syncthreads();

        const int tc = tid & 31, tr = tid >> 5;   // tr 0..31, 4 rows each
        float accY[4][4], accZ[4][4];
        #pragma unroll
        for (int r = 0; r < 4; r++)
            #pragma unroll
            for (int c = 0; c < 4; c++) { accY[r][c] = 0.f; accZ[r][c] = 0.f; }

        const int sr = tid >> 3, sc4 = (tid & 7) * 4;
        const bool stager = (sr < 64);
        const float* wsrc0 = (sr < 32) ? w3n : w3r;
        const int wrow = (sr < 32) ? sr : sr - 32;
        float* Bmine = S + ((sr < 32) ? 0 : 32 * 132);
        float4 bvv[4];
        if (stager) {
            #pragma unroll
            for (int i = 0; i < 4; i++)
                bvv[i] = *(const float4*)(wsrc0 + (size_t)(wrow + i * 32) * HID + sc4);
        }
        for (int ch = 0; ch < 4; ch++) {
            if (stager) {
                #pragma unroll
                for (int i = 0; i < 4; i++) {
                    int r = wrow + i * 32;
                    Bmine[(sc4 + 0) * 132 + r] = bvv[i].x;
                    Bmine[(sc4 + 1) * 132 + r] = bvv[i].y;
                    Bmine[(sc4 + 2) * 132 + r] = bvv[i].z;
                    Bmine[(sc4 + 3) * 132 + r] = bvv[i].w;
                }
            }
            __syncthreads();
            if (ch + 1 < 4 && stager) {
                #pragma unroll
                for (int i = 0; i < 4; i++)
                    bvv[i] = *(const float4*)(wsrc0 + (size_t)(wrow + i * 32) * HID
                                              + (ch + 1) * 32 + sc4);
            }
            for (int kq = 0; kq < 8; kq++) {
                float4 af[4];
                #pragma unroll
                for (int rr = 0; rr < 4; rr++)
                    af[rr] = *(const float4*)&xY[(tr * 4 + rr) * 132 + ch * 32 + kq * 4];
                #pragma unroll
                for (int kk = 0; kk < 4; kk++) {
                    int k = kq * 4 + kk;
                    float4 bn = *(const float4*)&S[k * 132 + tc * 4];
                    float4 br = *(const float4*)&S[32 * 132 + k * 132 + tc * 4];
                    #pragma unroll
                    for (int rr = 0; rr < 4; rr++) {
                        float a = (kk == 0) ? af[rr].x : (kk == 1) ? af[rr].y
                                 : (kk == 2) ? af[rr].z : af[rr].w;
                        accY[rr][0] += a * bn.x; accY[rr][1] += a * bn.y;
                        accY[rr][2] += a * bn.z; accY[rr][3] += a * bn.w;
                        accZ[rr][0] += a * br.x; accZ[rr][1] += a * br.y;
                        accZ[rr][2] += a * br.z; accZ[rr][3] += a * br.w;
                    }
                }
            }
            __syncthreads();
        }
        #pragma unroll
        for (int rr = 0; rr < 4; rr++) {
            float4 yv = {accY[rr][0], accY[rr][1], accY[rr][2], accY[rr][3]};
            *(float4*)&xY[(tr * 4 + rr) * 132 + tc * 4] = yv;
        }
        __syncthreads();

        float bias[4], pv[4];
        #pragma unroll
        for (int c = 0; c < 4; c++) {
            bias[c] = b3[tc * 4 + c];
            pv[c]   = p3[tc * 4 + c];
        }
        float a0 = p3[lane], a1 = p3[64 + lane];
        float pp = a0 * a0 + a1 * a1;
        #pragma unroll
        for (int o = 32; o >= 1; o >>= 1) pp += __shfl_xor(pp, o, 64);
        float nrm = sqrtf(pp);
        float outv[4][4];
        float* scpart = S;   // 128*32 = 4096
        #pragma unroll
        for (int rr = 0; rr < 4; rr++) {
            int m = tr * 4 + rr;
            int bg = off2[m], en = off2[m + 1];
            float s0 = 0.f, s1 = 0.f, s2 = 0.f, s3 = 0.f;
            for (int t = bg; t < en; t++) {
                float4 yv = *(const float4*)&xY[csr[t] * 132 + tc * 4];
                s0 += yv.x; s1 += yv.y; s2 += yv.z; s3 += yv.w;
            }
            float inv = 1.f / (float)((en - bg) > 1 ? (en - bg) : 1);
            outv[rr][0] = fmaxf(s0 * inv + accZ[rr][0] + bias[0], 0.f);
            outv[rr][1] = fmaxf(s1 * inv + accZ[rr][1] + bias[1], 0.f);
            outv[rr][2] = fmaxf(s2 * inv + accZ[rr][2] + bias[2], 0.f);
            outv[rr][3] = fmaxf(s3 * inv + accZ[rr][3] + bias[3], 0.f);
        }
        __syncthreads();
        #pragma unroll
        for (int rr = 0; rr < 4; rr++) {
            float sp = outv[rr][0] * pv[0] + outv[rr][1] * pv[1]
                     + outv[rr][2] * pv[2] + outv[rr][3] * pv[3];
            scpart[(tr * 4 + rr) * 32 + tc] = sp;
        }
        __syncthreads();
        if (tid < K2) {
            float sum = 0.f;
            #pragma unroll
            for (int t = 0; t < 32; t++) sum += scpart[tid * 32 + t];
            sc[tid] = tanhf(sum / nrm);
        }
        __syncthreads();
        int* posC = idsL;   // idsL dead since phase A gather
        if (tid < K2) {
            float scv = sc[tid];
            int rank = 0;
            for (int j = 0; j < K2; j++) {
                float o = sc[j];
                rank += (o > scv) || (o == scv && j < tid);
            }
            posC[tid] = (rank < K3) ? rank : -1;
        }
        __syncthreads();
        float cm[4], cs[4];
        #pragma unroll
        for (int c = 0; c < 4; c++) { cm[c] = -INFINITY; cs[c] = 0.f; }
        #pragma unroll
        for (int rr = 0; rr < 4; rr++) {
            int m = tr * 4 + rr;
            int r = posC[m];
            if (r < 0) continue;
            float sv = sc[m];
            #pragma unroll
            for (int c = 0; c < 4; c++) {
                float v = outv[rr][c] * sv;
                cm[c] = fmaxf(cm[c], v);
                cs[c] += v;
            }
        }
        __syncthreads();   // scpart dead before redM/redS reuse
        float* redM = S;
        float* redS = S + 32 * 128;
        #pragma unroll
        for (int c = 0; c < 4; c++) {
            redM[tr * 128 + tc * 4 + c] = cm[c];
            redS[tr * 128 + tc * 4 + c] = cs[c];
        }
        __syncthreads();
        if (tid < 128) {
            float mx = redM[tid], sm = redS[tid];
            #pragma unroll 4
            for (int t = 1; t < 32; t++) {
                mx = fmaxf(mx, redM[t * 128 + tid]);
                sm += redS[t * 128 + tid];
            }
            g3[g * 256 + tid] = mx;
            g3[g * 256 + 128 + tid] = sm / (float)K3;
        }
    }
}

// ---------------------------------------------------------------------------
// MLP head: h=g1+g2+g3; relu(h@lw1.T+lb1); relu(@lw2.T+lb2); sigmoid(@lw3.T+lb3)
__global__ __launch_bounds__(128) void k_mlp(const float* __restrict__ g1, const float* __restrict__ g2,
                      const float* __restrict__ g3,
                      const float* __restrict__ lw1, const float* __restrict__ lb1,
                      const float* __restrict__ lw2, const float* __restrict__ lb2,
                      const float* __restrict__ lw3, const float* __restrict__ lb3,
                      float* __restrict__ out) {
    int g = blockIdx.x, t = threadIdx.x;  // 128 threads
    __shared__ float h0[256];
    __shared__ float h1[128];
    __shared__ float h2r[64];
    h0[t]       = g1[g * 256 + t] + g2[g * 256 + t] + g3[g * 256 + t];
    h0[t + 128] = g1[g * 256 + 128 + t] + g2[g * 256 + 128 + t] + g3[g * 256 + 128 + t];
    __syncthreads();
    float a = lb1[t];
    #pragma unroll 4
    for (int j = 0; j < 256; j++) a += h0[j] * lw1[t * 256 + j];
    h1[t] = fmaxf(a, 0.f);
    __syncthreads();
    if (t < 64) {
        float a2 = lb2[t];
        #pragma unroll 4
        for (int j = 0; j < 128; j++) a2 += h1[j] * lw2[t * 128 + j];
        h2r[t] = fmaxf(a2, 0.f) * lw3[t];
    }
    __syncthreads();
    if (t == 0) {
        float s = 0.f;
        for (int j = 0; j < 64; j++) s += h2r[j];
        s += lb3[0];
        out[g] = 1.f / (1.f + expf(-s));
    }
}

// ---------------------------------------------------------------------------
extern "C" void kernel_launch(void* const* d_in, const int* in_sizes, int n_in,
                              void* d_out, int out_size, void* d_ws, size_t ws_size,
                              hipStream_t stream) {
    const int*   node_ids = (const int*)d_in[0];
    const int*   ei   = (const int*)d_in[1];   // edge_index (2, E)
    const float* emb  = (const float*)d_in[3];
    const float* w1n  = (const float*)d_in[4];
    const float* w1r  = (const float*)d_in[5];
    const float* b1   = (const float*)d_in[6];
    const float* w2n  = (const float*)d_in[7];
    const float* w2r  = (const float*)d_in[8];
    const float* b2   = (const float*)d_in[9];
    const float* w3n  = (const float*)d_in[10];
    const float* w3r  = (const float*)d_in[11];
    const float* b3   = (const float*)d_in[12];
    const float* p1   = (const float*)d_in[13];
    const float* p2   = (const float*)d_in[14];
    const float* p3   = (const float*)d_in[15];
    const float* lw1  = (const float*)d_in[16];
    const float* lb1  = (const float*)d_in[17];
    const float* lw2  = (const float*)d_in[18];
    const float* lb2  = (const float*)d_in[19];
    const float* lw3  = (const float*)d_in[20];
    const float* lb3  = (const float*)d_in[21];
    float* out = (float*)d_out;

    // Workspace: only the three global-pool buffers (1.5 MB).
    float* ws  = (float*)d_ws;
    float* g1  = ws;                 // B*256
    float* g2  = g1 + B * 2 * HID;   // B*256
    float* g3  = g2 + B * 2 * HID;   // B*256

    k_fused<<<B, 1024, 0, stream>>>(node_ids, emb, ei, ei + E,
                                    w1n, w1r, b1, p1,
                                    w2n, w2r, b2, p2,
                                    w3n, w3r, b3, p3,
                                    g1, g2, g3);
    k_mlp<<<B, 128, 0, stream>>>(g1, g2, g3, lw1, lb1, lw2, lb2, lw3, lb3, out);
}

// Round 18
// 353.313 us; speedup vs baseline: 1.7051x; 1.7051x over previous
//
#include <hip/hip_runtime.h>
#include <math.h>

// Problem constants (from reference)
constexpr int B    = 512;
constexpr int NPG  = 200;    // nodes per graph, stage 0
constexpr int EPER = 2000;   // edges per graph
constexpr int EMB  = 9;
constexpr int HID  = 128;
constexpr int K1   = 160;    // ceil(0.8*200)
constexpr int K2   = 128;    // ceil(0.8*160)
constexpr int K3   = 103;    // ceil(0.8*128)
constexpr int E    = B * EPER;  // 1024000

// Exclusive prefix scan over 256 ints by wave 0 (4 vals/lane + shfl_up).
__device__ __forceinline__ void scan_off(const int* deg, int* off2,
                                         int lane, int wv) {
    if (wv == 0) {
        int i0 = lane * 4;
        int v0 = deg[i0], v1 = deg[i0 + 1], v2 = deg[i0 + 2], v3 = deg[i0 + 3];
        int s1 = v0 + v1, s2 = s1 + v2, s3 = s2 + v3;
        int run = s3;
        #pragma unroll
        for (int o = 1; o < 64; o <<= 1) {
            int t = __shfl_up(run, o, 64);
            if (lane >= o) run += t;
        }
        int excl = run - s3;
        off2[i0]     = excl;
        off2[i0 + 1] = excl + v0;
        off2[i0 + 2] = excl + s1;
        off2[i0 + 3] = excl + s2;
        if (lane == 63) off2[256] = run;
    }
}

// ---------------------------------------------------------------------------
// ONE KERNEL for all three GNN stages, one graph per block (640 threads).
// r18 = r16 body (best: 359us) with reduced k-loop register demand:
//  - no weight prefetch (stage directly with a transient float4)  [-16 regs]
//  - af batch split 8 -> 2x4 (bn/br re-read per half: LDS broadcast, cheap)
//    [-16 regs]
// Evidence (r7 vs r13-r17): spill starts when unified VGPR+AGPR demand
// exceeds ~512/(waves per SIMD); at 640thr budget ~170, r16 demand ~200
// -> 33MB scratch. This cuts peak k-loop live to ~110.
// Tripwire: WRITE_SIZE ~1.6MB logical; >>8MB = still spilling = revert r16.
// GEMM layout stays the r4/r7-verified k-major form (no XOR swizzle).
__global__ __launch_bounds__(640, 1) void k_fused(
        const int* __restrict__ node_ids,
        const float* __restrict__ emb,
        const int* __restrict__ es, const int* __restrict__ ed,
        const float* __restrict__ w1n, const float* __restrict__ w1r,
        const float* __restrict__ b1, const float* __restrict__ p1,
        const float* __restrict__ w2n, const float* __restrict__ w2r,
        const float* __restrict__ b2, const float* __restrict__ p2,
        const float* __restrict__ w3n, const float* __restrict__ w3r,
        const float* __restrict__ b3, const float* __restrict__ p3,
        float* __restrict__ g1, float* __restrict__ g2,
        float* __restrict__ g3) {
    const int g = blockIdx.x, tid = threadIdx.x;
    const int lane = tid & 63, wv = tid >> 6;   // 10 waves

    __shared__ float xY[K1 * 132];              // 84.5 KB
    __shared__ float S[2 * 32 * 132];           // 33.8 KB scratch union
    __shared__ int   csr[EPER];                 // 8 KB
    __shared__ int   deg[256], off2[257], cur[256];
    __shared__ int   idsL[NPG];                 // reused as posC in phase C
    __shared__ float sc[NPG];
    __shared__ int   pos1[NPG], pos2[K1];

    const int eb = g * EPER, nb0 = g * NPG;

    // ======================= Phase A: stage 1 =======================
    {
        float* x0L  = S;          // 1800
        float* mnL  = S + 1800;   // 1800
        float* redA = S + 3600;   // 2560
        if (tid < NPG) idsL[tid] = node_ids[g * NPG + tid];
        if (tid < 256) deg[tid] = 0;
        __syncthreads();
        for (int i = tid; i < NPG * EMB; i += 640) {
            int n = i / EMB, j = i - n * EMB;
            x0L[i] = emb[(size_t)idsL[n] * EMB + j];
        }
        for (int e = tid; e < EPER; e += 640)
            atomicAdd(&deg[ed[eb + e] - nb0], 1);
        __syncthreads();
        scan_off(deg, off2, lane, wv);
        __syncthreads();
        if (tid < 256) cur[tid] = off2[tid];
        __syncthreads();
        for (int e = tid; e < EPER; e += 640) {
            int slot = atomicAdd(&cur[ed[eb + e] - nb0], 1);
            csr[slot] = es[eb + e] - nb0;
        }
        __syncthreads();
        if (tid < NPG) {
            int bg = off2[tid], en = off2[tid + 1];
            float a[EMB];
            #pragma unroll
            for (int j = 0; j < EMB; j++) a[j] = 0.f;
            for (int t = bg; t < en; t++) {
                int s = csr[t];
                #pragma unroll
                for (int j = 0; j < EMB; j++) a[j] += x0L[s * EMB + j];
            }
            float inv = 1.f / (float)((en - bg) > 1 ? (en - bg) : 1);
            #pragma unroll
            for (int j = 0; j < EMB; j++) mnL[tid * EMB + j] = a[j] * inv;
        }
        float pl0 = p1[lane], pl1 = p1[64 + lane];
        float pp = pl0 * pl0 + pl1 * pl1;
        #pragma unroll
        for (int o = 32; o >= 1; o >>= 1) pp += __shfl_xor(pp, o, 64);
        float nrm = sqrtf(pp);
        float wn0[EMB], wn1[EMB], wr0[EMB], wr1[EMB];
        #pragma unroll
        for (int j = 0; j < EMB; j++) {
            wn0[j] = w1n[lane * EMB + j];
            wn1[j] = w1n[(lane + 64) * EMB + j];
            wr0[j] = w1r[lane * EMB + j];
            wr1[j] = w1r[(lane + 64) * EMB + j];
        }
        float bb0 = b1[lane], bb1 = b1[64 + lane];
        __syncthreads();
        for (int i = wv; i < NPG; i += 10) {
            float c0 = bb0, c1 = bb1;
            #pragma unroll
            for (int j = 0; j < EMB; j++) {
                float m = mnL[i * EMB + j];
                float x = x0L[i * EMB + j];
                c0 += m * wn0[j] + x * wr0[j];
                c1 += m * wn1[j] + x * wr1[j];
            }
            c0 = fmaxf(c0, 0.f);
            c1 = fmaxf(c1, 0.f);
            float d = c0 * pl0 + c1 * pl1;
            #pragma unroll
            for (int o = 32; o >= 1; o >>= 1) d += __shfl_xor(d, o, 64);
            if (lane == 0) sc[i] = tanhf(d / nrm);
        }
        __syncthreads();
        if (tid < NPG) {
            float scv = sc[tid];
            int rank = 0;
            for (int j = 0; j < NPG; j++) {
                float o = sc[j];
                rank += (o > scv) || (o == scv && j < tid);
            }
            pos1[tid] = (rank < K1) ? rank : -1;
        }
        __syncthreads();
        float pm0 = -INFINITY, pm1 = -INFINITY, ps0 = 0.f, ps1 = 0.f;
        for (int i = wv; i < NPG; i += 10) {
            int r = pos1[i];
            if (r < 0) continue;
            float c0 = bb0, c1 = bb1;
            #pragma unroll
            for (int j = 0; j < EMB; j++) {
                float m = mnL[i * EMB + j];
                float x = x0L[i * EMB + j];
                c0 += m * wn0[j] + x * wr0[j];
                c1 += m * wn1[j] + x * wr1[j];
            }
            float s = sc[i];
            float v0 = fmaxf(c0, 0.f) * s;
            float v1 = fmaxf(c1, 0.f) * s;
            xY[r * 132 + lane] = v0;
            xY[r * 132 + 64 + lane] = v1;
            pm0 = fmaxf(pm0, v0); ps0 += v0;
            pm1 = fmaxf(pm1, v1); ps1 += v1;
        }
        redA[wv * 128 + lane] = pm0;
        redA[wv * 128 + 64 + lane] = pm1;
        redA[1280 + wv * 128 + lane] = ps0;
        redA[1280 + wv * 128 + 64 + lane] = ps1;
        __syncthreads();
        if (tid < 128) {
            float mx = redA[tid], sm = redA[1280 + tid];
            #pragma unroll
            for (int w = 1; w < 10; w++) {
                mx = fmaxf(mx, redA[w * 128 + tid]);
                sm += redA[1280 + w * 128 + tid];
            }
            g1[g * 256 + tid] = mx;
            g1[g * 256 + 128 + tid] = sm / (float)K1;
        }
        __syncthreads();
    }

    // ======================= Phase B: stage 2 =======================
    {
        if (tid < 256) deg[tid] = 0;
        __syncthreads();
        for (int e = tid; e < EPER; e += 640) {
            int a = pos1[es[eb + e] - nb0];
            int b = pos1[ed[eb + e] - nb0];
            if (a >= 0 && b >= 0) atomicAdd(&deg[b], 1);
        }
        __syncthreads();
        scan_off(deg, off2, lane, wv);
        __syncthreads();
        if (tid < 256) cur[tid] = off2[tid];
        __syncthreads();
        for (int e = tid; e < EPER; e += 640) {
            int a = pos1[es[eb + e] - nb0];
            int b = pos1[ed[eb + e] - nb0];
            if (a >= 0 && b >= 0) {
                int slot = atomicAdd(&cur[b], 1);
                csr[slot] = a;
            }
        }

        const int tc = tid & 31, tr = tid >> 5;   // tr 0..19
        float accY[8][4], accZ[8][4];
        #pragma unroll
        for (int r = 0; r < 8; r++)
            #pragma unroll
            for (int c = 0; c < 4; c++) { accY[r][c] = 0.f; accZ[r][c] = 0.f; }

        const int sr = tid >> 3, sc4 = (tid & 7) * 4;
        const bool stager = (sr < 64);
        const float* wsrc0 = (sr < 32) ? w2n : w2r;
        const int wrow = (sr < 32) ? sr : sr - 32;
        float* Bmine = S + ((sr < 32) ? 0 : 32 * 132);
        for (int ch = 0; ch < 4; ch++) {
            __syncthreads();   // prev chunk's reads done (covers csr too at ch=0)
            if (stager) {
                #pragma unroll
                for (int i = 0; i < 4; i++) {
                    int r = wrow + i * 32;
                    float4 v = *(const float4*)(wsrc0 + (size_t)r * HID
                                                + ch * 32 + sc4);
                    Bmine[(sc4 + 0) * 132 + r] = v.x;
                    Bmine[(sc4 + 1) * 132 + r] = v.y;
                    Bmine[(sc4 + 2) * 132 + r] = v.z;
                    Bmine[(sc4 + 3) * 132 + r] = v.w;
                }
            }
            __syncthreads();
            for (int kq = 0; kq < 8; kq++) {
                #pragma unroll
                for (int rh = 0; rh < 2; rh++) {
                    float4 af[4];
                    #pragma unroll
                    for (int rr = 0; rr < 4; rr++)
                        af[rr] = *(const float4*)&xY[(tr * 8 + rh * 4 + rr) * 132
                                                     + ch * 32 + kq * 4];
                    #pragma unroll
                    for (int kk = 0; kk < 4; kk++) {
                        int k = kq * 4 + kk;
                        float4 bn = *(const float4*)&S[k * 132 + tc * 4];
                        float4 br = *(const float4*)&S[32 * 132 + k * 132 + tc * 4];
                        #pragma unroll
                        for (int rr = 0; rr < 4; rr++) {
                            int R = rh * 4 + rr;
                            float a = (kk == 0) ? af[rr].x : (kk == 1) ? af[rr].y
                                     : (kk == 2) ? af[rr].z : af[rr].w;
                            accY[R][0] += a * bn.x; accY[R][1] += a * bn.y;
                            accY[R][2] += a * bn.z; accY[R][3] += a * bn.w;
                            accZ[R][0] += a * br.x; accZ[R][1] += a * br.y;
                            accZ[R][2] += a * br.z; accZ[R][3] += a * br.w;
                        }
                    }
                }
            }
        }
        __syncthreads();   // all k-loop xY reads done before Y overwrite
        #pragma unroll
        for (int rr = 0; rr < 8; rr++) {
            float4 yv = {accY[rr][0], accY[rr][1], accY[rr][2], accY[rr][3]};
            *(float4*)&xY[(tr * 8 + rr) * 132 + tc * 4] = yv;
        }
        __syncthreads();

        float bias[4], pv[4];
        #pragma unroll
        for (int c = 0; c < 4; c++) {
            bias[c] = b2[tc * 4 + c];
            pv[c]   = p2[tc * 4 + c];
        }
        float a0 = p2[lane], a1 = p2[64 + lane];
        float pp = a0 * a0 + a1 * a1;
        #pragma unroll
        for (int o = 32; o >= 1; o >>= 1) pp += __shfl_xor(pp, o, 64);
        float nrm = sqrtf(pp);
        float outv[8][4];
        #pragma unroll
        for (int rr = 0; rr < 8; rr++) {
            int m = tr * 8 + rr;
            int bg = off2[m], en = off2[m + 1];
            float s0 = 0.f, s1 = 0.f, s2 = 0.f, s3 = 0.f;
            for (int t = bg; t < en; t++) {
                float4 yv = *(const float4*)&xY[csr[t] * 132 + tc * 4];
                s0 += yv.x; s1 += yv.y; s2 += yv.z; s3 += yv.w;
            }
            float inv = 1.f / (float)((en - bg) > 1 ? (en - bg) : 1);
            outv[rr][0] = fmaxf(s0 * inv + accZ[rr][0] + bias[0], 0.f);
            outv[rr][1] = fmaxf(s1 * inv + accZ[rr][1] + bias[1], 0.f);
            outv[rr][2] = fmaxf(s2 * inv + accZ[rr][2] + bias[2], 0.f);
            outv[rr][3] = fmaxf(s3 * inv + accZ[rr][3] + bias[3], 0.f);
        }
        float* scpart = S;
        __syncthreads();
        #pragma unroll
        for (int rr = 0; rr < 8; rr++) {
            float sp = outv[rr][0] * pv[0] + outv[rr][1] * pv[1]
                     + outv[rr][2] * pv[2] + outv[rr][3] * pv[3];
            scpart[(tr * 8 + rr) * 32 + tc] = sp;
        }
        __syncthreads();
        if (tid < K1) {
            float sum = 0.f;
            #pragma unroll
            for (int t = 0; t < 32; t++) sum += scpart[tid * 32 + t];
            sc[tid] = tanhf(sum / nrm);
        }
        __syncthreads();
        if (tid < K1) {
            float scv = sc[tid];
            int rank = 0;
            for (int j = 0; j < K1; j++) {
                float o = sc[j];
                rank += (o > scv) || (o == scv && j < tid);
            }
            pos2[tid] = (rank < K2) ? rank : -1;
        }
        __syncthreads();
        float cm[4], cs[4];
        #pragma unroll
        for (int c = 0; c < 4; c++) { cm[c] = -INFINITY; cs[c] = 0.f; }
        #pragma unroll
        for (int rr = 0; rr < 8; rr++) {
            int m = tr * 8 + rr;
            int r = pos2[m];
            if (r < 0) continue;
            float sv = sc[m];
            float v0 = outv[rr][0] * sv, v1 = outv[rr][1] * sv;
            float v2 = outv[rr][2] * sv, v3 = outv[rr][3] * sv;
            cm[0] = fmaxf(cm[0], v0); cs[0] += v0;
            cm[1] = fmaxf(cm[1], v1); cs[1] += v1;
            cm[2] = fmaxf(cm[2], v2); cs[2] += v2;
            cm[3] = fmaxf(cm[3], v3); cs[3] += v3;
            float4 o0 = {v0, v1, v2, v3};
            *(float4*)&xY[r * 132 + tc * 4] = o0;   // x2p stays in LDS
        }
        float* redM = S;
        float* redS = S + 20 * 128;
        #pragma unroll
        for (int c = 0; c < 4; c++) {
            redM[tr * 128 + tc * 4 + c] = cm[c];
            redS[tr * 128 + tc * 4 + c] = cs[c];
        }
        __syncthreads();
        if (tid < 128) {
            float mx = redM[tid], sm = redS[tid];
            #pragma unroll 4
            for (int t = 1; t < 20; t++) {
                mx = fmaxf(mx, redM[t * 128 + tid]);
                sm += redS[t * 128 + tid];
            }
            g2[g * 256 + tid] = mx;
            g2[g * 256 + 128 + tid] = sm / (float)K2;
        }
        __syncthreads();
    }

    // ======================= Phase C: stage 3 =======================
    {
        if (tid < 256) deg[tid] = 0;
        __syncthreads();
        for (int e = tid; e < EPER; e += 640) {
            int a = pos1[es[eb + e] - nb0];
            int b = pos1[ed[eb + e] - nb0];
            a = (a >= 0) ? pos2[a] : -1;
            b = (b >= 0) ? pos2[b] : -1;
            if (a >= 0 && b >= 0) atomicAdd(&deg[b], 1);
        }
        __syncthreads();
        scan_off(deg, off2, lane, wv);
        __syncthreads();
        if (tid < 256) cur[tid] = off2[tid];
        __syncthreads();
        for (int e = tid; e < EPER; e += 640) {
            int a = pos1[es[eb + e] - nb0];
            int b = pos1[ed[eb + e] - nb0];
            a = (a >= 0) ? pos2[a] : -1;
            b = (b >= 0) ? pos2[b] : -1;
            if (a >= 0 && b >= 0) {
                int slot = atomicAdd(&cur[b], 1);
                csr[slot] = a;
            }
        }

        const int tc = tid & 31, tr = tid >> 5;   // use tr<16
        const bool comp = (tid < 512);
        float accY[8][4], accZ[8][4];
        #pragma unroll
        for (int r = 0; r < 8; r++)
            #pragma unroll
            for (int c = 0; c < 4; c++) { accY[r][c] = 0.f; accZ[r][c] = 0.f; }

        const int sr = tid >> 3, sc4 = (tid & 7) * 4;
        const bool stager = (sr < 64);
        const float* wsrc0 = (sr < 32) ? w3n : w3r;
        const int wrow = (sr < 32) ? sr : sr - 32;
        float* Bmine = S + ((sr < 32) ? 0 : 32 * 132);
        for (int ch = 0; ch < 4; ch++) {
            __syncthreads();
            if (stager) {
                #pragma unroll
                for (int i = 0; i < 4; i++) {
                    int r = wrow + i * 32;
                    float4 v = *(const float4*)(wsrc0 + (size_t)r * HID
                                                + ch * 32 + sc4);
                    Bmine[(sc4 + 0) * 132 + r] = v.x;
                    Bmine[(sc4 + 1) * 132 + r] = v.y;
                    Bmine[(sc4 + 2) * 132 + r] = v.z;
                    Bmine[(sc4 + 3) * 132 + r] = v.w;
                }
            }
            __syncthreads();
            if (comp) {
                for (int kq = 0; kq < 8; kq++) {
                    #pragma unroll
                    for (int rh = 0; rh < 2; rh++) {
                        float4 af[4];
                        #pragma unroll
                        for (int rr = 0; rr < 4; rr++)
                            af[rr] = *(const float4*)&xY[(tr * 8 + rh * 4 + rr) * 132
                                                         + ch * 32 + kq * 4];
                        #pragma unroll
                        for (int kk = 0; kk < 4; kk++) {
                            int k = kq * 4 + kk;
                            float4 bn = *(const float4*)&S[k * 132 + tc * 4];
                            float4 br = *(const float4*)&S[32 * 132 + k * 132 + tc * 4];
                            #pragma unroll
                            for (int rr = 0; rr < 4; rr++) {
                                int R = rh * 4 + rr;
                                float a = (kk == 0) ? af[rr].x : (kk == 1) ? af[rr].y
                                         : (kk == 2) ? af[rr].z : af[rr].w;
                                accY[R][0] += a * bn.x; accY[R][1] += a * bn.y;
                                accY[R][2] += a * bn.z; accY[R][3] += a * bn.w;
                                accZ[R][0] += a * br.x; accZ[R][1] += a * br.y;
                                accZ[R][2] += a * br.z; accZ[R][3] += a * br.w;
                            }
                        }
                    }
                }
            }
        }
        __syncthreads();
        if (comp) {
            #pragma unroll
            for (int rr = 0; rr < 8; rr++) {
                float4 yv = {accY[rr][0], accY[rr][1], accY[rr][2], accY[rr][3]};
                *(float4*)&xY[(tr * 8 + rr) * 132 + tc * 4] = yv;
            }
        }
        __syncthreads();

        float bias[4], pv[4];
        #pragma unroll
        for (int c = 0; c < 4; c++) {
            bias[c] = b3[tc * 4 + c];
            pv[c]   = p3[tc * 4 + c];
        }
        float a0 = p3[lane], a1 = p3[64 + lane];
        float pp = a0 * a0 + a1 * a1;
        #pragma unroll
        for (int o = 32; o >= 1; o >>= 1) pp += __shfl_xor(pp, o, 64);
        float nrm = sqrtf(pp);
        float outv[8][4];
        float* scpart = S;
        if (comp) {
            #pragma unroll
            for (int rr = 0; rr < 8; rr++) {
                int m = tr * 8 + rr;
                int bg = off2[m], en = off2[m + 1];
                float s0 = 0.f, s1 = 0.f, s2 = 0.f, s3 = 0.f;
                for (int t = bg; t < en; t++) {
                    float4 yv = *(const float4*)&xY[csr[t] * 132 + tc * 4];
                    s0 += yv.x; s1 += yv.y; s2 += yv.z; s3 += yv.w;
                }
                float inv = 1.f / (float)((en - bg) > 1 ? (en - bg) : 1);
                outv[rr][0] = fmaxf(s0 * inv + accZ[rr][0] + bias[0], 0.f);
                outv[rr][1] = fmaxf(s1 * inv + accZ[rr][1] + bias[1], 0.f);
                outv[rr][2] = fmaxf(s2 * inv + accZ[rr][2] + bias[2], 0.f);
                outv[rr][3] = fmaxf(s3 * inv + accZ[rr][3] + bias[3], 0.f);
            }
        }
        __syncthreads();
        if (comp) {
            #pragma unroll
            for (int rr = 0; rr < 8; rr++) {
                float sp = outv[rr][0] * pv[0] + outv[rr][1] * pv[1]
                         + outv[rr][2] * pv[2] + outv[rr][3] * pv[3];
                scpart[(tr * 8 + rr) * 32 + tc] = sp;
            }
        }
        __syncthreads();
        if (tid < K2) {
            float sum = 0.f;
            #pragma unroll
            for (int t = 0; t < 32; t++) sum += scpart[tid * 32 + t];
            sc[tid] = tanhf(sum / nrm);
        }
        __syncthreads();
        int* posC = idsL;   // idsL dead since phase A gather
        if (tid < K2) {
            float scv = sc[tid];
            int rank = 0;
            for (int j = 0; j < K2; j++) {
                float o = sc[j];
                rank += (o > scv) || (o == scv && j < tid);
            }
            posC[tid] = (rank < K3) ? rank : -1;
        }
        __syncthreads();
        float cm[4], cs[4];
        #pragma unroll
        for (int c = 0; c < 4; c++) { cm[c] = -INFINITY; cs[c] = 0.f; }
        if (comp) {
            #pragma unroll
            for (int rr = 0; rr < 8; rr++) {
                int m = tr * 8 + rr;
                int r = posC[m];
                if (r < 0) continue;
                float sv = sc[m];
                #pragma unroll
                for (int c = 0; c < 4; c++) {
                    float v = outv[rr][c] * sv;
                    cm[c] = fmaxf(cm[c], v);
                    cs[c] += v;
                }
            }
        }
        float* redM = S;
        float* redS = S + 16 * 128;
        if (comp) {
            #pragma unroll
            for (int c = 0; c < 4; c++) {
                redM[tr * 128 + tc * 4 + c] = cm[c];
                redS[tr * 128 + tc * 4 + c] = cs[c];
            }
        }
        __syncthreads();
        if (tid < 128) {
            float mx = redM[tid], sm = redS[tid];
            #pragma unroll 4
            for (int t = 1; t < 16; t++) {
                mx = fmaxf(mx, redM[t * 128 + tid]);
                sm += redS[t * 128 + tid];
            }
            g3[g * 256 + tid] = mx;
            g3[g * 256 + 128 + tid] = sm / (float)K3;
        }
    }
}

// ---------------------------------------------------------------------------
// MLP head: h=g1+g2+g3; relu(h@lw1.T+lb1); relu(@lw2.T+lb2); sigmoid(@lw3.T+lb3)
__global__ __launch_bounds__(128) void k_mlp(const float* __restrict__ g1, const float* __restrict__ g2,
                      const float* __restrict__ g3,
                      const float* __restrict__ lw1, const float* __restrict__ lb1,
                      const float* __restrict__ lw2, const float* __restrict__ lb2,
                      const float* __restrict__ lw3, const float* __restrict__ lb3,
                      float* __restrict__ out) {
    int g = blockIdx.x, t = threadIdx.x;  // 128 threads
    __shared__ float h0[256];
    __shared__ float h1[128];
    __shared__ float h2r[64];
    h0[t]       = g1[g * 256 + t] + g2[g * 256 + t] + g3[g * 256 + t];
    h0[t + 128] = g1[g * 256 + 128 + t] + g2[g * 256 + 128 + t] + g3[g * 256 + 128 + t];
    __syncthreads();
    float a = lb1[t];
    #pragma unroll 4
    for (int j = 0; j < 256; j++) a += h0[j] * lw1[t * 256 + j];
    h1[t] = fmaxf(a, 0.f);
    __syncthreads();
    if (t < 64) {
        float a2 = lb2[t];
        #pragma unroll 4
        for (int j = 0; j < 128; j++) a2 += h1[j] * lw2[t * 128 + j];
        h2r[t] = fmaxf(a2, 0.f) * lw3[t];
    }
    __syncthreads();
    if (t == 0) {
        float s = 0.f;
        for (int j = 0; j < 64; j++) s += h2r[j];
        s += lb3[0];
        out[g] = 1.f / (1.f + expf(-s));
    }
}

// ---------------------------------------------------------------------------
extern "C" void kernel_launch(void* const* d_in, const int* in_sizes, int n_in,
                              void* d_out, int out_size, void* d_ws, size_t ws_size,
                              hipStream_t stream) {
    const int*   node_ids = (const int*)d_in[0];
    const int*   ei   = (const int*)d_in[1];   // edge_index (2, E)
    const float* emb  = (const float*)d_in[3];
    const float* w1n  = (const float*)d_in[4];
    const float* w1r  = (const float*)d_in[5];
    const float* b1   = (const float*)d_in[6];
    const float* w2n  = (const float*)d_in[7];
    const float* w2r  = (const float*)d_in[8];
    const float* b2   = (const float*)d_in[9];
    const float* w3n  = (const float*)d_in[10];
    const float* w3r  = (const float*)d_in[11];
    const float* b3   = (const float*)d_in[12];
    const float* p1   = (const float*)d_in[13];
    const float* p2   = (const float*)d_in[14];
    const float* p3   = (const float*)d_in[15];
    const float* lw1  = (const float*)d_in[16];
    const float* lb1  = (const float*)d_in[17];
    const float* lw2  = (const float*)d_in[18];
    const float* lb2  = (const float*)d_in[19];
    const float* lw3  = (const float*)d_in[20];
    const float* lb3  = (const float*)d_in[21];
    float* out = (float*)d_out;

    // Workspace: only the three global-pool buffers (1.5 MB).
    float* ws  = (float*)d_ws;
    float* g1  = ws;                 // B*256
    float* g2  = g1 + B * 2 * HID;   // B*256
    float* g3  = g2 + B * 2 * HID;   // B*256

    k_fused<<<B, 640, 0, stream>>>(node_ids, emb, ei, ei + E,
                                   w1n, w1r, b1, p1,
                                   w2n, w2r, b2, p2,
                                   w3n, w3r, b3, p3,
                                   g1, g2, g3);
    k_mlp<<<B, 128, 0, stream>>>(g1, g2, g3, lw1, lb1, lw2, lb2, lw3, lb3, out);
}